// Round 1
// baseline (4956.853 us; speedup 1.0000x reference)
//
#include <hip/hip_runtime.h>

#define B_   128
#define S_   256
#define EMB_ 256
#define H_   1024
#define NH3  3072

#define G_      4     // batch groups
#define NW      64    // workgroups per batch group
#define MG      32    // batch rows per group
#define HS      16    // H columns per workgroup
#define THREADS 384   // 6 waves

typedef _Float16 f16;
typedef _Float16 h8 __attribute__((ext_vector_type(8)));
typedef float    f4 __attribute__((ext_vector_type(4)));

// ---------- gather + fp16 convert: xe16[(s*128+b)*256 + k] = emb[x[b][s]][k]
__global__ void gather_kernel(const int* __restrict__ x, const float* __restrict__ emb,
                              f16* __restrict__ xe16) {
  int m = blockIdx.x;           // 0..32767  (m = s*128 + b)
  int k = threadIdx.x;          // 0..255
  int b = m & 127, s = m >> 7;
  int row = x[b * S_ + s];
  xe16[m * EMB_ + k] = (f16)emb[row * EMB_ + k];
}

// ---------- transpose + fp16 convert: out[n*K + k] = (f16) in[k*N + n]
__global__ void transpose_cvt(const float* __restrict__ in, f16* __restrict__ out,
                              int K, int N) {
  __shared__ float tile[32][33];
  int n0 = blockIdx.x * 32, k0 = blockIdx.y * 32;
  int tx = threadIdx.x & 31, ty = threadIdx.x >> 5;  // 32 x 8
#pragma unroll
  for (int i = 0; i < 4; ++i)
    tile[ty + 8 * i][tx] = in[(k0 + ty + 8 * i) * N + n0 + tx];
  __syncthreads();
#pragma unroll
  for (int i = 0; i < 4; ++i)
    out[(n0 + ty + 8 * i) * K + k0 + tx] = (f16)tile[tx][ty + 8 * i];
}

// ---------- group barrier (device-scope, 64 WGs per batch group)
__device__ __forceinline__ void group_barrier(int* c, int target) {
  __syncthreads();
  if (threadIdx.x == 0) {
    __hip_atomic_fetch_add(c, 1, __ATOMIC_RELEASE, __HIP_MEMORY_SCOPE_AGENT);
    while (__hip_atomic_load(c, __ATOMIC_RELAXED, __HIP_MEMORY_SCOPE_AGENT) < target)
      __builtin_amdgcn_s_sleep(1);
  }
  __syncthreads();
  // every thread acquires (ctr is monotonic; any read >= released value syncs)
  (void)__hip_atomic_load(c, __ATOMIC_ACQUIRE, __HIP_MEMORY_SCOPE_AGENT);
}

// ---------- persistent GRU kernel
__launch_bounds__(THREADS, 2)
__global__ void gru_kernel(const f16* __restrict__ xe16, const f16* __restrict__ Ut,
                           const f16* __restrict__ Wt, const float* __restrict__ hidden,
                           const float* __restrict__ bvec, float* __restrict__ out,
                           f16* __restrict__ h16, int* __restrict__ ctr) {
  __shared__ f16   h_lds[MG * H_];        // 64 KB, XOR-swizzled rows of 2048B
  __shared__ f16   xe_lds[MG * EMB_];     // 16 KB, XOR-swizzled rows of 512B
  __shared__ float rec_lds[MG][65];       // cols: 0-15 z, 16-31 r, 32-47 hh_x, 48-63 hh_u
  __shared__ float hold_lds[MG][HS];      // f32 h state slice (exact)
  __shared__ float b0_lds[48], b1_lds[48];

  const int tid = threadIdx.x;
  const int bid = blockIdx.x;
  const int g   = bid & 3;          // batch group (spreads groups across XCDs)
  const int w   = bid >> 2;         // 0..63 H-slice
  const int gb0 = g * MG;
  const int hc0 = w * HS;

  const int lane = tid & 63;
  const int wv   = tid >> 6;        // 0..5
  const int mt   = wv & 1;          // M tile (16 rows)
  const int nt   = wv >> 1;         // 0..2 gate tile (z / r / hh)
  const int ln   = lane & 15;
  const int klo  = lane >> 4;       // 0..3

  int* cptr = &ctr[g * 64];

  // ---- U & W fragments resident in registers for the whole kernel
  h8 uf[32]; h8 wf[8];
  {
    int col = nt * H_ + hc0 + ln;                 // global U/W column (n index)
    const f16* up = Ut + col * H_ + klo * 8;
#pragma unroll
    for (int kt = 0; kt < 32; ++kt) uf[kt] = *(const h8*)(up + kt * 32);
    const f16* wp = Wt + col * EMB_ + klo * 8;
#pragma unroll
    for (int kt = 0; kt < 8; ++kt) wf[kt] = *(const h8*)(wp + kt * 32);
  }
  if (tid < 48) {
    int col = (tid >> 4) * H_ + hc0 + (tid & 15);
    b0_lds[tid] = bvec[col];
    b1_lds[tid] = bvec[NH3 + col];
  }
  // ---- init h state (f32 local slice + fp16 global buffer 0)
  for (int idx = tid; idx < MG * HS; idx += THREADS) {
    int bl = idx >> 4, jl = idx & 15;
    float hv = hidden[(gb0 + bl) * H_ + hc0 + jl];
    hold_lds[bl][jl] = hv;
    h16[(gb0 + bl) * H_ + hc0 + jl] = (f16)hv;
  }
  group_barrier(cptr, NW);

  for (int t = 0; t < S_; ++t) {
    const f16* hcur = h16 + (t & 1) * (B_ * H_);
    f16*       hnxt = h16 + ((t + 1) & 1) * (B_ * H_);

    // ---- stage h group slab (32 x 1024 fp16) into swizzled LDS
    {
      const uint4* src = (const uint4*)(hcur + gb0 * H_);
      for (int idx = tid; idx < MG * H_ / 8; idx += THREADS) {   // 4096 chunks
        int row = idx >> 7, c = idx & 127;
        uint4 v = src[idx];
        *(uint4*)((char*)h_lds + row * 2048 + ((c * 16) ^ ((row & 7) << 4))) = v;
      }
    }
    // ---- stage xe slab (32 x 256 fp16)
    {
      const uint4* src = (const uint4*)(xe16 + (t * B_ + gb0) * EMB_);
      for (int idx = tid; idx < MG * EMB_ / 8; idx += THREADS) { // 1024 chunks
        int row = idx >> 5, c = idx & 31;
        uint4 v = src[idx];
        *(uint4*)((char*)xe_lds + row * 512 + ((c * 16) ^ ((row & 7) << 4))) = v;
      }
    }
    __syncthreads();

    // ---- MFMA: accW = xe@W slice, accU = h@U slice (separate for hh gate)
    f4 accW = {0.f, 0.f, 0.f, 0.f}, accU0 = {0.f, 0.f, 0.f, 0.f}, accU1 = {0.f, 0.f, 0.f, 0.f};
    const int   arow  = mt * 16 + ln;
    const char* hbase = (const char*)h_lds + arow * 2048;
    const char* xbase = (const char*)xe_lds + arow * 512;
    const int   rmask = (arow & 7) << 4;
#pragma unroll
    for (int kt = 0; kt < 8; ++kt) {
      h8 a = *(const h8*)(xbase + ((kt * 64 + klo * 16) ^ rmask));
      accW = __builtin_amdgcn_mfma_f32_16x16x32_f16(a, wf[kt], accW, 0, 0, 0);
    }
#pragma unroll
    for (int kt = 0; kt < 32; kt += 2) {
      h8 a0 = *(const h8*)(hbase + ((kt * 64 + klo * 16) ^ rmask));
      accU0 = __builtin_amdgcn_mfma_f32_16x16x32_f16(a0, uf[kt], accU0, 0, 0, 0);
      h8 a1 = *(const h8*)(hbase + (((kt + 1) * 64 + klo * 16) ^ rmask));
      accU1 = __builtin_amdgcn_mfma_f32_16x16x32_f16(a1, uf[kt + 1], accU1, 0, 0, 0);
    }
#pragma unroll
    for (int j = 0; j < 4; ++j) {
      int r = mt * 16 + klo * 4 + j;
      float u = accU0[j] + accU1[j];
      if (nt < 2) rec_lds[r][nt * 16 + ln] = accW[j] + u;
      else { rec_lds[r][32 + ln] = accW[j]; rec_lds[r][48 + ln] = u; }
    }
    __syncthreads();

    // ---- gates (f32)
    for (int idx = tid; idx < MG * HS; idx += THREADS) {
      int bl = idx >> 4, jl = idx & 15;
      float az = rec_lds[bl][jl]      + b0_lds[jl]      + b1_lds[jl];
      float ar = rec_lds[bl][16 + jl] + b0_lds[16 + jl] + b1_lds[16 + jl];
      float xh = rec_lds[bl][32 + jl] + b0_lds[32 + jl];
      float rh = rec_lds[bl][48 + jl] + b1_lds[32 + jl];
      float z  = 1.f / (1.f + __expf(-az));
      float r  = 1.f / (1.f + __expf(-ar));
      float hh = 1.f - 2.f / (1.f + __expf(2.f * (xh + r * rh)));
      float hp = hold_lds[bl][jl];
      float hn = z * hp + (1.f - z) * hh;
      hold_lds[bl][jl] = hn;
      out[((gb0 + bl) * S_ + t) * H_ + hc0 + jl] = hn;
      hnxt[(gb0 + bl) * H_ + hc0 + jl] = (f16)hn;
      if (t == S_ - 1)
        out[(size_t)B_ * S_ * H_ + (gb0 + bl) * H_ + hc0 + jl] = hn;
    }
    group_barrier(cptr, NW * (t + 2));
  }
}

extern "C" void kernel_launch(void* const* d_in, const int* in_sizes, int n_in,
                              void* d_out, int out_size, void* d_ws, size_t ws_size,
                              hipStream_t stream) {
  const int*   x      = (const int*)  d_in[0];
  const float* hidden = (const float*)d_in[1];
  const float* emb    = (const float*)d_in[2];
  const float* W      = (const float*)d_in[3];
  const float* U      = (const float*)d_in[4];
  const float* bvec   = (const float*)d_in[5];
  float* out = (float*)d_out;

  char* ws = (char*)d_ws;
  f16* Ut   = (f16*)(ws);                   //  6,291,456 B
  f16* Wt   = (f16*)(ws + 6291456);         //  1,572,864 B
  f16* xe16 = (f16*)(ws + 7864320);         // 16,777,216 B
  f16* h16  = (f16*)(ws + 24641536);        //    524,288 B (double buffer)
  int* ctr  = (int*)(ws + 25165824);        //      1,024 B

  hipMemsetAsync(ctr, 0, 1024, stream);
  hipLaunchKernelGGL(transpose_cvt, dim3(NH3 / 32, H_ / 32), dim3(256), 0, stream,
                     U, Ut, H_, NH3);
  hipLaunchKernelGGL(transpose_cvt, dim3(NH3 / 32, EMB_ / 32), dim3(256), 0, stream,
                     W, Wt, EMB_, NH3);
  hipLaunchKernelGGL(gather_kernel, dim3(B_ * S_), dim3(EMB_), 0, stream, x, emb, xe16);

  void* args[] = { (void*)&xe16, (void*)&Ut, (void*)&Wt, (void*)&hidden,
                   (void*)&bvec, (void*)&out, (void*)&h16, (void*)&ctr };
  hipLaunchCooperativeKernel(reinterpret_cast<void*>(gru_kernel),
                             dim3(G_ * NW), dim3(THREADS), args, 0, stream);
}

// Round 2
// 1451.137 us; speedup vs baseline: 3.4158x; 3.4158x over previous
//
#include <hip/hip_runtime.h>

#define B_   128
#define S_   256
#define EMB_ 256
#define H_   1024
#define NH3  3072

#define G_      4     // batch groups
#define NW      64    // workgroups per batch group
#define MG      32    // batch rows per group
#define HS      16    // H columns per workgroup
#define THREADS 384   // 6 waves

typedef _Float16 f16;
typedef _Float16 h8 __attribute__((ext_vector_type(8)));
typedef float    f4 __attribute__((ext_vector_type(4)));
typedef unsigned long long u64;

// ---------- gather + fp16 convert: xe16[(s*128+b)*256 + k] = emb[x[b][s]][k]
__global__ void gather_kernel(const int* __restrict__ x, const float* __restrict__ emb,
                              f16* __restrict__ xe16) {
  int m = blockIdx.x;           // m = s*128 + b
  int k = threadIdx.x;          // 0..255
  int b = m & 127, s = m >> 7;
  int row = x[b * S_ + s];
  xe16[m * EMB_ + k] = (f16)emb[row * EMB_ + k];
}

// ---------- transpose + fp16 convert: out[n*K + k] = (f16) in[k*N + n]
__global__ void transpose_cvt(const float* __restrict__ in, f16* __restrict__ out,
                              int K, int N) {
  __shared__ float tile[32][33];
  int n0 = blockIdx.x * 32, k0 = blockIdx.y * 32;
  int tx = threadIdx.x & 31, ty = threadIdx.x >> 5;  // 32 x 8
#pragma unroll
  for (int i = 0; i < 4; ++i)
    tile[ty + 8 * i][tx] = in[(k0 + ty + 8 * i) * N + n0 + tx];
  __syncthreads();
#pragma unroll
  for (int i = 0; i < 4; ++i)
    out[(n0 + ty + 8 * i) * K + k0 + tx] = (f16)tile[tx][ty + 8 * i];
}

// ---------- persistent GRU kernel
__launch_bounds__(THREADS, 2)
__global__ void gru_kernel(const f16* __restrict__ xe16, const f16* __restrict__ Ut,
                           const f16* __restrict__ Wt, const float* __restrict__ hidden,
                           const float* __restrict__ bvec, float* __restrict__ out,
                           f16* __restrict__ h16, int* __restrict__ ctr) {
  __shared__ f16   h_lds[MG * H_];        // 64 KB, XOR-swizzled rows of 2048B
  __shared__ f16   xe_lds[2][MG * EMB_];  // 2 x 16 KB, XOR-swizzled rows of 512B
  __shared__ float rec_lds[MG][65];       // cols: 0-15 z, 16-31 r, 32-47 hh_x, 48-63 hh_u
  __shared__ float hold_lds[MG][HS];      // f32 h state slice (exact)
  __shared__ float b0_lds[48], b1_lds[48];

  const int tid = threadIdx.x;
  const int bid = blockIdx.x;
  const int g   = bid & 3;          // batch group
  const int w   = bid >> 2;         // 0..63 H-slice
  const int gb0 = g * MG;
  const int hc0 = w * HS;

  const int lane = tid & 63;
  const int wv   = tid >> 6;        // 0..5
  const int mt   = wv & 1;          // M tile (16 rows)
  const int nt   = wv >> 1;         // 0..2 gate tile (z / r / hh)
  const int ln   = lane & 15;
  const int klo  = lane >> 4;       // 0..3

  int* cptr = &ctr[g * 64];

  // ---- U & W fragments resident in registers for the whole kernel (pinned)
  h8 uf[32]; h8 wf[8];
  {
    int col = nt * H_ + hc0 + ln;
    const f16* up = Ut + col * H_ + klo * 8;
#pragma unroll
    for (int kt = 0; kt < 32; ++kt) uf[kt] = *(const h8*)(up + kt * 32);
    const f16* wp = Wt + col * EMB_ + klo * 8;
#pragma unroll
    for (int kt = 0; kt < 8; ++kt) wf[kt] = *(const h8*)(wp + kt * 32);
  }
#pragma unroll
  for (int kt = 0; kt < 32; ++kt) asm volatile("" : "+v"(uf[kt]));
#pragma unroll
  for (int kt = 0; kt < 8; ++kt) asm volatile("" : "+v"(wf[kt]));

  if (tid < 48) {
    int col = (tid >> 4) * H_ + hc0 + (tid & 15);
    b0_lds[tid] = bvec[col];
    b1_lds[tid] = bvec[NH3 + col];
  }

  // ---- init h state (f32 local slice + coherent fp16 store to buffer 0)
  for (int idx = tid; idx < MG * HS; idx += THREADS) {
    int bl = idx >> 4, jl = idx & 15;
    float hv = hidden[(gb0 + bl) * H_ + hc0 + jl];
    hold_lds[bl][jl] = hv;
    unsigned short hb = __builtin_bit_cast(unsigned short, (f16)hv);
    __hip_atomic_store((unsigned short*)&h16[(gb0 + bl) * H_ + hc0 + jl], hb,
                       __ATOMIC_RELAXED, __HIP_MEMORY_SCOPE_AGENT);
  }
  asm volatile("s_waitcnt vmcnt(0)" ::: "memory");
  __syncthreads();
  if (tid == 0)
    __hip_atomic_fetch_add(cptr, 1, __ATOMIC_RELAXED, __HIP_MEMORY_SCOPE_AGENT);

  // ---- stage xe(0) into buffer 0 while waiting
  {
    const uint4* src = (const uint4*)(xe16 + (0 * B_ + gb0) * EMB_);
    uint4 t0 = src[tid], t1 = src[tid + THREADS];
    uint4 t2; if (tid < 256) t2 = src[tid + 2 * THREADS];
#pragma unroll
    for (int i = 0; i < 2; ++i) {
      int idx = tid + i * THREADS, row = idx >> 5, c = idx & 31;
      *(uint4*)((char*)xe_lds[0] + row * 512 + ((c * 16) ^ ((row & 7) << 4))) = (i ? t1 : t0);
    }
    if (tid < 256) {
      int idx = tid + 2 * THREADS, row = idx >> 5, c = idx & 31;
      *(uint4*)((char*)xe_lds[0] + row * 512 + ((c * 16) ^ ((row & 7) << 4))) = t2;
    }
  }
  if (tid == 0)
    while (__hip_atomic_load(cptr, __ATOMIC_RELAXED, __HIP_MEMORY_SCOPE_AGENT) < NW)
      __builtin_amdgcn_s_sleep(1);
  __syncthreads();

  for (int t = 0; t < S_; ++t) {
    const f16* hcur = h16 + (t & 1) * (B_ * H_);
    f16*       hnxt = h16 + ((t + 1) & 1) * (B_ * H_);

    // ---- stage h group slab (32 x 1024 fp16) via coherent 8B loads, two-phase
    {
      const u64* src = (const u64*)(hcur + gb0 * H_);
      u64 tmp[21];
#pragma unroll
      for (int i = 0; i < 21; ++i)
        tmp[i] = __hip_atomic_load(src + tid + i * THREADS,
                                   __ATOMIC_RELAXED, __HIP_MEMORY_SCOPE_AGENT);
      u64 tr = 0;
      if (tid < 128)
        tr = __hip_atomic_load(src + tid + 21 * THREADS,
                               __ATOMIC_RELAXED, __HIP_MEMORY_SCOPE_AGENT);
#pragma unroll
      for (int i = 0; i < 21; ++i) {
        int idx = tid + i * THREADS, row = idx >> 8, c = idx & 255;
        *(u64*)((char*)h_lds + row * 2048 + ((c * 8) ^ ((row & 7) << 4))) = tmp[i];
      }
      if (tid < 128) {
        int idx = tid + 21 * THREADS, row = idx >> 8, c = idx & 255;
        *(u64*)((char*)h_lds + row * 2048 + ((c * 8) ^ ((row & 7) << 4))) = tr;
      }
    }
    __syncthreads();

    // ---- MFMA: accW = xe@W slice, accU = h@U slice (separate for hh gate)
    f4 accW = {0.f, 0.f, 0.f, 0.f}, accU0 = {0.f, 0.f, 0.f, 0.f}, accU1 = {0.f, 0.f, 0.f, 0.f};
    const int   arow  = mt * 16 + ln;
    const char* hbase = (const char*)h_lds + arow * 2048;
    const char* xbase = (const char*)xe_lds[t & 1] + arow * 512;
    const int   rmask = (arow & 7) << 4;
#pragma unroll
    for (int kt = 0; kt < 8; ++kt) {
      h8 a = *(const h8*)(xbase + ((kt * 64 + klo * 16) ^ rmask));
      accW = __builtin_amdgcn_mfma_f32_16x16x32_f16(a, wf[kt], accW, 0, 0, 0);
    }
#pragma unroll
    for (int kt = 0; kt < 32; kt += 2) {
      h8 a0 = *(const h8*)(hbase + ((kt * 64 + klo * 16) ^ rmask));
      accU0 = __builtin_amdgcn_mfma_f32_16x16x32_f16(a0, uf[kt], accU0, 0, 0, 0);
      h8 a1 = *(const h8*)(hbase + (((kt + 1) * 64 + klo * 16) ^ rmask));
      accU1 = __builtin_amdgcn_mfma_f32_16x16x32_f16(a1, uf[kt + 1], accU1, 0, 0, 0);
    }
#pragma unroll
    for (int j = 0; j < 4; ++j) {
      int r = mt * 16 + klo * 4 + j;
      float u = accU0[j] + accU1[j];
      if (nt < 2) rec_lds[r][nt * 16 + ln] = accW[j] + u;
      else { rec_lds[r][32 + ln] = accW[j]; rec_lds[r][48 + ln] = u; }
    }
    __syncthreads();

    // ---- gates (f32), coherent h stores, cached out stores
    for (int idx = tid; idx < MG * HS; idx += THREADS) {
      int bl = idx >> 4, jl = idx & 15;
      float az = rec_lds[bl][jl]      + b0_lds[jl]      + b1_lds[jl];
      float ar = rec_lds[bl][16 + jl] + b0_lds[16 + jl] + b1_lds[16 + jl];
      float xh = rec_lds[bl][32 + jl] + b0_lds[32 + jl];
      float rh = rec_lds[bl][48 + jl] + b1_lds[32 + jl];
      float z  = 1.f / (1.f + __expf(-az));
      float r  = 1.f / (1.f + __expf(-ar));
      float hh = 1.f - 2.f / (1.f + __expf(2.f * (xh + r * rh)));
      float hp = hold_lds[bl][jl];
      float hn = z * hp + (1.f - z) * hh;
      hold_lds[bl][jl] = hn;
      out[((gb0 + bl) * S_ + t) * H_ + hc0 + jl] = hn;
      unsigned short hb = __builtin_bit_cast(unsigned short, (f16)hn);
      __hip_atomic_store((unsigned short*)&hnxt[(gb0 + bl) * H_ + hc0 + jl], hb,
                         __ATOMIC_RELAXED, __HIP_MEMORY_SCOPE_AGENT);
      if (t == S_ - 1)
        out[(size_t)B_ * S_ * H_ + (gb0 + bl) * H_ + hc0 + jl] = hn;
    }
    // ---- completion-ordered arrival: wait own stores, then relaxed add
    asm volatile("s_waitcnt vmcnt(0)" ::: "memory");
    __syncthreads();
    if (tid == 0)
      __hip_atomic_fetch_add(cptr, 1, __ATOMIC_RELAXED, __HIP_MEMORY_SCOPE_AGENT);

    // ---- stage xe(t+1) into the other buffer while waiting for stragglers
    if (t + 1 < S_) {
      const uint4* src = (const uint4*)(xe16 + ((t + 1) * B_ + gb0) * EMB_);
      uint4 t0 = src[tid], t1 = src[tid + THREADS];
      uint4 t2; if (tid < 256) t2 = src[tid + 2 * THREADS];
      char* dst = (char*)xe_lds[(t + 1) & 1];
#pragma unroll
      for (int i = 0; i < 2; ++i) {
        int idx = tid + i * THREADS, row = idx >> 5, c = idx & 31;
        *(uint4*)(dst + row * 512 + ((c * 16) ^ ((row & 7) << 4))) = (i ? t1 : t0);
      }
      if (tid < 256) {
        int idx = tid + 2 * THREADS, row = idx >> 5, c = idx & 31;
        *(uint4*)(dst + row * 512 + ((c * 16) ^ ((row & 7) << 4))) = t2;
      }
    }
    if (tid == 0) {
      int target = NW * (t + 2);
      while (__hip_atomic_load(cptr, __ATOMIC_RELAXED, __HIP_MEMORY_SCOPE_AGENT) < target)
        __builtin_amdgcn_s_sleep(1);
    }
    __syncthreads();
  }
}

extern "C" void kernel_launch(void* const* d_in, const int* in_sizes, int n_in,
                              void* d_out, int out_size, void* d_ws, size_t ws_size,
                              hipStream_t stream) {
  const int*   x      = (const int*)  d_in[0];
  const float* hidden = (const float*)d_in[1];
  const float* emb    = (const float*)d_in[2];
  const float* W      = (const float*)d_in[3];
  const float* U      = (const float*)d_in[4];
  const float* bvec   = (const float*)d_in[5];
  float* out = (float*)d_out;

  char* ws = (char*)d_ws;
  f16* Ut   = (f16*)(ws);                   //  6,291,456 B
  f16* Wt   = (f16*)(ws + 6291456);         //  1,572,864 B
  f16* xe16 = (f16*)(ws + 7864320);         // 16,777,216 B
  f16* h16  = (f16*)(ws + 24641536);        //    524,288 B (double buffer)
  int* ctr  = (int*)(ws + 25165824);        //      1,024 B

  hipMemsetAsync(ctr, 0, 1024, stream);
  hipLaunchKernelGGL(transpose_cvt, dim3(NH3 / 32, H_ / 32), dim3(256), 0, stream,
                     U, Ut, H_, NH3);
  hipLaunchKernelGGL(transpose_cvt, dim3(NH3 / 32, EMB_ / 32), dim3(256), 0, stream,
                     W, Wt, EMB_, NH3);
  hipLaunchKernelGGL(gather_kernel, dim3(B_ * S_), dim3(EMB_), 0, stream, x, emb, xe16);

  void* args[] = { (void*)&xe16, (void*)&Ut, (void*)&Wt, (void*)&hidden,
                   (void*)&bvec, (void*)&out, (void*)&h16, (void*)&ctr };
  hipLaunchCooperativeKernel(reinterpret_cast<void*>(gru_kernel),
                             dim3(G_ * NW), dim3(THREADS), args, 0, stream);
}

// Round 5
// 1052.836 us; speedup vs baseline: 4.7081x; 1.3783x over previous
//
#include <hip/hip_runtime.h>

#define B_   128
#define S_   256
#define EMB_ 256
#define H_   1024
#define NH3  3072

#define G_      8     // batch groups
#define NW      32    // workgroups per group
#define MG      16    // batch rows per group
#define HS      32    // H columns per workgroup
#define THREADS 768   // 12 waves

typedef _Float16 f16;
typedef _Float16 h8 __attribute__((ext_vector_type(8)));
typedef float    f4 __attribute__((ext_vector_type(4)));
typedef unsigned long long u64;

// ---------- gather + fp16 convert
__global__ void gather_kernel(const int* __restrict__ x, const float* __restrict__ emb,
                              f16* __restrict__ xe16) {
  int m = blockIdx.x, k = threadIdx.x;
  int b = m & 127, s = m >> 7;
  int row = x[b * S_ + s];
  xe16[m * EMB_ + k] = (f16)emb[row * EMB_ + k];
}

// ---------- transpose + fp16 convert: out[n*K + k] = (f16) in[k*N + n]
__global__ void transpose_cvt(const float* __restrict__ in, f16* __restrict__ out,
                              int K, int N) {
  __shared__ float tile[32][33];
  int n0 = blockIdx.x * 32, k0 = blockIdx.y * 32;
  int tx = threadIdx.x & 31, ty = threadIdx.x >> 5;
#pragma unroll
  for (int i = 0; i < 4; ++i)
    tile[ty + 8 * i][tx] = in[(k0 + ty + 8 * i) * N + n0 + tx];
  __syncthreads();
#pragma unroll
  for (int i = 0; i < 4; ++i)
    out[(n0 + ty + 8 * i) * K + k0 + tx] = (f16)tile[tx][ty + 8 * i];
}

// ---------- persistent GRU kernel (round-2-proven exchange protocol)
__launch_bounds__(THREADS, 3)
__global__ void gru_kernel(const f16* __restrict__ xe16, const f16* __restrict__ Ut,
                           const f16* __restrict__ Wt, const float* __restrict__ hidden,
                           const float* __restrict__ bvec, float* __restrict__ out,
                           f16* __restrict__ h16, int* __restrict__ ctr) {
  __shared__ f16   h_lds[MG * H_];        // 32 KB, rows of 2048B, XOR-swizzled
  __shared__ f16   xe_lds[2][MG * EMB_];  // 16 KB, rows of 512B, XOR-swizzled
  __shared__ float recS[4][MG][100];      // K-split partials: z[0..31] r[32..63] xh[64..95]
  __shared__ float recU[4][MG][36];       // K-split partials: rh[0..31]

  const int tid = threadIdx.x;
  const int bid = blockIdx.x;
  const int g   = bid & 7;
  const int w   = bid >> 3;         // 0..31
  const int gb0 = g * MG;
  const int hc0 = w * HS;

  const int lane = tid & 63;
  const int wv   = tid >> 6;        // 0..11
  const int ksp  = wv & 3;          // K quarter
  const int cp   = wv >> 2;         // gate 0=z 1=r 2=hh
  const int ln   = lane & 15;
  const int klo  = lane >> 4;
  const int bl   = tid >> 5;        // gate row (tid<512)
  const int jl   = tid & 31;

  // ---- weights register-resident: per wave one gate, 2 col-tiles, K-quarter
  h8 uf0[8], uf1[8], wf0[2], wf1[2];
  {
    const f16* u0 = Ut + (size_t)(cp * H_ + hc0 + ln) * H_ + ksp * 256 + klo * 8;
    const f16* u1 = u0 + (size_t)16 * H_;
#pragma unroll
    for (int kt = 0; kt < 8; ++kt) { uf0[kt] = *(const h8*)(u0 + kt * 32);
                                     uf1[kt] = *(const h8*)(u1 + kt * 32); }
    const f16* w0 = Wt + (size_t)(cp * H_ + hc0 + ln) * EMB_ + ksp * 64 + klo * 8;
    const f16* w1 = w0 + 16 * EMB_;
#pragma unroll
    for (int kt = 0; kt < 2; ++kt) { wf0[kt] = *(const h8*)(w0 + kt * 32);
                                     wf1[kt] = *(const h8*)(w1 + kt * 32); }
  }
#pragma unroll
  for (int kt = 0; kt < 8; ++kt) { asm volatile("" : "+v"(uf0[kt])); asm volatile("" : "+v"(uf1[kt])); }
  asm volatile("" : "+v"(wf0[0]), "+v"(wf0[1]), "+v"(wf1[0]), "+v"(wf1[1]));

  // ---- per-thread gate state: h in register, biases in registers
  float hprev = 0.f, bz = 0.f, brr = 0.f, bxh = 0.f, brh = 0.f;
  size_t obase = 0, hoff = 0;
  if (tid < 512) {
    int col = hc0 + jl;
    bz  = bvec[col] + bvec[NH3 + col];
    brr = bvec[H_ + col] + bvec[NH3 + H_ + col];
    bxh = bvec[2 * H_ + col];
    brh = bvec[NH3 + 2 * H_ + col];
    hprev = hidden[(size_t)(gb0 + bl) * H_ + col];
    obase = ((size_t)(gb0 + bl) * S_) * H_ + col;
    hoff  = (size_t)(gb0 + bl) * H_ + col;
  }

  // ---- stage h(0) from `hidden` (f32 -> f16, swizzled); no cross-WG sync needed
  for (int idx = tid; idx < MG * H_ / 4; idx += THREADS) {   // 4096 float4 chunks
    int r = idx >> 8, c4 = idx & 255;
    float4 hv = ((const float4*)(hidden + (size_t)(gb0 + r) * H_))[c4];
    unsigned lo = ((unsigned)__builtin_bit_cast(unsigned short, (f16)hv.y) << 16)
                |  (unsigned)__builtin_bit_cast(unsigned short, (f16)hv.x);
    unsigned hi = ((unsigned)__builtin_bit_cast(unsigned short, (f16)hv.w) << 16)
                |  (unsigned)__builtin_bit_cast(unsigned short, (f16)hv.z);
    uint2 pk = {lo, hi};
    *(uint2*)((char*)h_lds + r * 2048 + ((c4 * 8) ^ ((r & 7) << 4))) = pk;
  }
  // ---- stage xe(0)
  for (int idx = tid; idx < MG * EMB_ / 8; idx += THREADS) { // 512 chunks
    uint4 v = ((const uint4*)(xe16 + (size_t)gb0 * EMB_))[idx];
    int r = idx >> 5, c = idx & 31;
    *(uint4*)((char*)xe_lds[0] + r * 512 + ((c * 16) ^ ((r & 7) << 4))) = v;
  }
  __syncthreads();

  for (int t = 0; t < S_; ++t) {
    // ---- pull h(t) slab (32 KB) via agent-scope atomic loads (proven path)
    if (t > 0) {
      const u64* src = (const u64*)(h16 + (size_t)(t & 1) * (B_ * H_) + (size_t)gb0 * H_);
      u64 v0 = __hip_atomic_load(src + tid,               __ATOMIC_RELAXED, __HIP_MEMORY_SCOPE_AGENT);
      u64 v1 = __hip_atomic_load(src + tid + THREADS,     __ATOMIC_RELAXED, __HIP_MEMORY_SCOPE_AGENT);
      u64 v2 = __hip_atomic_load(src + tid + 2 * THREADS, __ATOMIC_RELAXED, __HIP_MEMORY_SCOPE_AGENT);
      u64 v3 = __hip_atomic_load(src + tid + 3 * THREADS, __ATOMIC_RELAXED, __HIP_MEMORY_SCOPE_AGENT);
      u64 v4 = __hip_atomic_load(src + tid + 4 * THREADS, __ATOMIC_RELAXED, __HIP_MEMORY_SCOPE_AGENT);
      u64 v5 = 0;
      if (tid < 256)
        v5 = __hip_atomic_load(src + 3840 + tid, __ATOMIC_RELAXED, __HIP_MEMORY_SCOPE_AGENT);
      { int idx = tid;               int r = idx >> 8, c = idx & 255;
        *(u64*)((char*)h_lds + r * 2048 + ((c * 8) ^ ((r & 7) << 4))) = v0; }
      { int idx = tid + THREADS;     int r = idx >> 8, c = idx & 255;
        *(u64*)((char*)h_lds + r * 2048 + ((c * 8) ^ ((r & 7) << 4))) = v1; }
      { int idx = tid + 2 * THREADS; int r = idx >> 8, c = idx & 255;
        *(u64*)((char*)h_lds + r * 2048 + ((c * 8) ^ ((r & 7) << 4))) = v2; }
      { int idx = tid + 3 * THREADS; int r = idx >> 8, c = idx & 255;
        *(u64*)((char*)h_lds + r * 2048 + ((c * 8) ^ ((r & 7) << 4))) = v3; }
      { int idx = tid + 4 * THREADS; int r = idx >> 8, c = idx & 255;
        *(u64*)((char*)h_lds + r * 2048 + ((c * 8) ^ ((r & 7) << 4))) = v4; }
      if (tid < 256) {
        int idx = 3840 + tid;        int r = idx >> 8, c = idx & 255;
        *(u64*)((char*)h_lds + r * 2048 + ((c * 8) ^ ((r & 7) << 4))) = v5;
      }
      __syncthreads();
    }

    // ---- MFMA: U (16 MFMAs) + W (4) per wave, shared A-frags
    f4 a0 = {0.f,0.f,0.f,0.f}, a1 = {0.f,0.f,0.f,0.f};
    f4 a2 = {0.f,0.f,0.f,0.f}, a3 = {0.f,0.f,0.f,0.f};
    const char* hb = (const char*)h_lds + ln * 2048;
    const char* xb = (const char*)xe_lds[t & 1] + ln * 512;
    const int rm = (ln & 7) << 4;
#pragma unroll
    for (int kt = 0; kt < 8; ++kt) {
      h8 a = *(const h8*)(hb + ((ksp * 512 + kt * 64 + klo * 16) ^ rm));
      a0 = __builtin_amdgcn_mfma_f32_16x16x32_f16(a, uf0[kt], a0, 0, 0, 0);
      a1 = __builtin_amdgcn_mfma_f32_16x16x32_f16(a, uf1[kt], a1, 0, 0, 0);
    }
#pragma unroll
    for (int kt = 0; kt < 2; ++kt) {
      h8 aw = *(const h8*)(xb + ((ksp * 128 + kt * 64 + klo * 16) ^ rm));
      a2 = __builtin_amdgcn_mfma_f32_16x16x32_f16(aw, wf0[kt], a2, 0, 0, 0);
      a3 = __builtin_amdgcn_mfma_f32_16x16x32_f16(aw, wf1[kt], a3, 0, 0, 0);
    }
#pragma unroll
    for (int j = 0; j < 4; ++j) {
      int r = klo * 4 + j;
      if (cp < 2) {
        recS[ksp][r][cp * 32 + ln]      = a0[j] + a2[j];
        recS[ksp][r][cp * 32 + 16 + ln] = a1[j] + a3[j];
      } else {
        recS[ksp][r][64 + ln] = a2[j];
        recS[ksp][r][80 + ln] = a3[j];
        recU[ksp][r][ln]      = a0[j];
        recU[ksp][r][16 + ln] = a1[j];
      }
    }
    __syncthreads();

    // ---- gates (f32, h state in registers)
    float outv = 0.f;
    if (tid < 512) {
      float az = recS[0][bl][jl] + recS[1][bl][jl] + recS[2][bl][jl] + recS[3][bl][jl] + bz;
      float ar = recS[0][bl][32+jl] + recS[1][bl][32+jl] + recS[2][bl][32+jl] + recS[3][bl][32+jl] + brr;
      float xh = recS[0][bl][64+jl] + recS[1][bl][64+jl] + recS[2][bl][64+jl] + recS[3][bl][64+jl] + bxh;
      float rhu = recU[0][bl][jl] + recU[1][bl][jl] + recU[2][bl][jl] + recU[3][bl][jl] + brh;
      float z  = 1.f / (1.f + __expf(-az));
      float r  = 1.f / (1.f + __expf(-ar));
      float hh = 1.f - 2.f / (1.f + __expf(2.f * (xh + r * rhu)));
      float hn = z * hprev + (1.f - z) * hh;
      hprev = hn; outv = hn;
      if (t < S_ - 1) {
        unsigned short hb16 = __builtin_bit_cast(unsigned short, (f16)hn);
        __hip_atomic_store((unsigned short*)(h16 + (size_t)((t + 1) & 1) * (B_ * H_)) + hoff,
                           hb16, __ATOMIC_RELAXED, __HIP_MEMORY_SCOPE_AGENT);
      }
    }
    if (t == S_ - 1) {
      if (tid < 512) {
        out[obase + (size_t)t * H_] = outv;
        out[(size_t)B_ * S_ * H_ + hoff] = outv;
      }
      break;
    }

    // ---- drain own h-stores, then group barrier (round-2-proven protocol)
    asm volatile("s_waitcnt vmcnt(0)" ::: "memory");
    __syncthreads();
    if (tid == 0)
      __hip_atomic_fetch_add(&ctr[g], 1, __ATOMIC_RELAXED, __HIP_MEMORY_SCOPE_AGENT);

    // ---- overlap the spin window: deferred out stores + xe(t+1) staging
    if (tid < 512) {
      out[obase + (size_t)t * H_] = outv;
    } else {
      const uint4* src = (const uint4*)(xe16 + ((size_t)(t + 1) * B_ + gb0) * EMB_);
      char* dst = (char*)xe_lds[(t + 1) & 1];
#pragma unroll
      for (int i = 0; i < 2; ++i) {
        int idx = (tid - 512) * 2 + i;
        uint4 v = src[idx];
        int r = idx >> 5, c = idx & 31;
        *(uint4*)(dst + r * 512 + ((c * 16) ^ ((r & 7) << 4))) = v;
      }
    }
    if (tid == 0) {
      int target = NW * (t + 1);
      while (__hip_atomic_load(&ctr[g], __ATOMIC_RELAXED, __HIP_MEMORY_SCOPE_AGENT) < target)
        __builtin_amdgcn_s_sleep(1);
    }
    __syncthreads();
  }
}

extern "C" void kernel_launch(void* const* d_in, const int* in_sizes, int n_in,
                              void* d_out, int out_size, void* d_ws, size_t ws_size,
                              hipStream_t stream) {
  const int*   x      = (const int*)  d_in[0];
  const float* hidden = (const float*)d_in[1];
  const float* emb    = (const float*)d_in[2];
  const float* W      = (const float*)d_in[3];
  const float* U      = (const float*)d_in[4];
  const float* bvec   = (const float*)d_in[5];
  float* out = (float*)d_out;

  char* ws = (char*)d_ws;
  f16* Ut    = (f16*)(ws);                   //  6,291,456 B
  f16* Wt    = (f16*)(ws + 6291456);         //  1,572,864 B
  f16* xe16  = (f16*)(ws + 7864320);         // 16,777,216 B
  f16* h16   = (f16*)(ws + 24641536);        //    524,288 B (double buffer)
  int* ctr   = (int*)(ws + 25165824);        //    64 B

  hipMemsetAsync(ctr, 0, 64, stream);
  hipLaunchKernelGGL(transpose_cvt, dim3(NH3 / 32, H_ / 32), dim3(256), 0, stream,
                     U, Ut, H_, NH3);
  hipLaunchKernelGGL(transpose_cvt, dim3(NH3 / 32, EMB_ / 32), dim3(256), 0, stream,
                     W, Wt, EMB_, NH3);
  hipLaunchKernelGGL(gather_kernel, dim3(B_ * S_), dim3(EMB_), 0, stream, x, emb, xe16);

  void* args[] = { (void*)&xe16, (void*)&Ut, (void*)&Wt, (void*)&hidden,
                   (void*)&bvec, (void*)&out, (void*)&h16, (void*)&ctr };
  hipLaunchCooperativeKernel(reinterpret_cast<void*>(gru_kernel),
                             dim3(G_ * NW), dim3(THREADS), args, 0, stream);
}